// Round 4
// baseline (20.470 us; speedup 1.0000x reference)
//
#include <hip/hip_runtime.h>

// GradLoss: mean((sobelx(t)-sobelx(o))^2) + mean((sobely(t)-sobely(o))^2)
//         = mean(sobelx(d)^2) + mean(sobely(d)^2), d = t - o   (linearity)
//
// Stage1: barrier-free, LDS-free. Each wave owns a 256-col x 8-row strip
//   (1 float4 per lane per row). Load phase issues ALL 20 dwordx4 loads for
//   the strip (register array, static indexing), then compute phase does the
//   separable stencil with intra-wave shuffles for horizontal halos and the
//   half-row seam via one edge-lane scalar load. 4096 waves / 1024 blocks
//   -> 16 waves/CU for latency hiding. XCD-swizzled block ids give each XCD
//   a contiguous 4-image chunk so halo re-reads hit its L2.
// Stage2: one block reduces 4096 partials -> d_out.

#define BATCH 32
#define HH 512
#define WW 512
#define RW 8                        // output rows per wave
#define TPB 256
#define WPI 128                     // waves per image: (512/RW=64) ystrips * 2 xhalves
#define NPART (BATCH * WPI)         // 4096 partials
#define NBLK (NPART / 4)            // 1024 blocks (4 waves each)

__global__ __launch_bounds__(TPB, 4) void sobel_partial_kernel(
    const float* __restrict__ out_img,
    const float* __restrict__ tgt_img,
    float* __restrict__ partials)
{
    const int tid  = threadIdx.x;
    const int lane = tid & 63;
    // XCD swizzle: 1024 blocks, 8 XCDs -> contiguous 128-block (4-image) chunks
    const int b    = (blockIdx.x & 7) * (NBLK / 8) + (blockIdx.x >> 3);
    const int w    = b * (TPB / 64) + (tid >> 6);   // global wave id, 0..4095
    const int img  = w >> 7;                        // / WPI
    const int r    = w & (WPI - 1);
    const int y0   = (r >> 1) * RW;
    const int xh   = r & 1;
    const int x0   = (xh << 8) + lane * 4;          // this lane's 4 columns

    const size_t base = (size_t)img * HH * WW;
    const float* ob = out_img + base;
    const float* tb = tgt_img + base;

    // seam: xh=0 needs col 256 (lane 63's right halo), xh=1 needs col 255
    // (lane 0's left halo). Non-loader lanes keep 0 (image edge pad).
    const int  seamcol = xh ? 255 : 256;
    const bool loader  = xh ? (lane == 0) : (lane == 63);

    // ---- load phase: issue all 20 dwordx4 (+2 seam dwords) ----
    float4 dv[RW + 2];
    float  sm[RW + 2];
    #pragma unroll
    for (int i = 0; i < RW + 2; ++i) {
        const int g = y0 - 1 + i;                   // wave-uniform row
        if ((unsigned)g < (unsigned)HH) {
            const size_t ro = (size_t)g * WW;
            const float4 o = *(const float4*)(ob + ro + x0);
            const float4 t = *(const float4*)(tb + ro + x0);
            dv[i] = make_float4(t.x - o.x, t.y - o.y, t.z - o.z, t.w - o.w);
            float s = 0.f;
            if (loader) s = tb[ro + seamcol] - ob[ro + seamcol];
            sm[i] = s;
        } else {
            dv[i] = make_float4(0.f, 0.f, 0.f, 0.f);
            sm[i] = 0.f;
        }
    }

    // ---- compute phase: separable stencil, 3-row ring ----
    // row pass: hs = L + 2m + R (for gy), hd = R - L (for gx)
    // col pass: gx = hd_top + 2 hd_mid + hd_bot, gy = hs_top - hs_bot
    float hs[3][4], hd[3][4];
    float acc = 0.f;
    #pragma unroll
    for (int i = 0; i < RW + 2; ++i) {
        const float4 d = dv[i];
        float dl = __shfl_up(d.w, 1, 64);
        if (lane == 0)  dl = sm[i];     // xh0: 0 (edge); xh1: d[col 255]
        float dr = __shfl_down(d.x, 1, 64);
        if (lane == 63) dr = sm[i];     // xh0: d[col 256]; xh1: 0 (edge)

        const int cur = i % 3;
        hs[cur][0] = fmaf(2.f, d.x, dl  + d.y);  hd[cur][0] = d.y - dl;
        hs[cur][1] = fmaf(2.f, d.y, d.x + d.z);  hd[cur][1] = d.z - d.x;
        hs[cur][2] = fmaf(2.f, d.z, d.y + d.w);  hd[cur][2] = d.w - d.y;
        hs[cur][3] = fmaf(2.f, d.w, d.z + dr);   hd[cur][3] = dr  - d.z;

        if (i >= 2) {
            const int top = (i - 2) % 3;
            const int mid = (i - 1) % 3;
            #pragma unroll
            for (int j = 0; j < 4; ++j) {
                const float gx = fmaf(2.f, hd[mid][j], hd[top][j] + hd[cur][j]);
                const float gy = hs[top][j] - hs[cur][j];
                acc = fmaf(gx, gx, acc);
                acc = fmaf(gy, gy, acc);
            }
        }
    }

    // wave reduction; one plain store per wave
    #pragma unroll
    for (int off = 32; off > 0; off >>= 1)
        acc += __shfl_down(acc, off, 64);
    if (lane == 0)
        partials[w] = acc;
}

__global__ __launch_bounds__(TPB) void reduce_partials_kernel(
    const float* __restrict__ partials, float* __restrict__ out)
{
    const int tid = threadIdx.x;
    float s = 0.f;
    #pragma unroll
    for (int i = 0; i < NPART / (TPB * 4); ++i) {
        const float4 v = *(const float4*)(partials + (tid + i * TPB) * 4);
        s += (v.x + v.y) + (v.z + v.w);
    }
    #pragma unroll
    for (int off = 32; off > 0; off >>= 1)
        s += __shfl_down(s, off, 64);
    __shared__ float wsum[TPB / 64];
    if ((tid & 63) == 0) wsum[tid >> 6] = s;
    __syncthreads();
    if (tid == 0)
        out[0] = (wsum[0] + wsum[1] + wsum[2] + wsum[3])
               * (1.0f / ((float)BATCH * HH * WW));
}

extern "C" void kernel_launch(void* const* d_in, const int* in_sizes, int n_in,
                              void* d_out, int out_size, void* d_ws, size_t ws_size,
                              hipStream_t stream) {
    (void)in_sizes; (void)n_in; (void)ws_size; (void)out_size;
    const float* out_img = (const float*)d_in[0];   // "output"
    const float* tgt_img = (const float*)d_in[1];   // "target"
    float* partials = (float*)d_ws;
    float* res = (float*)d_out;

    sobel_partial_kernel<<<NBLK, TPB, 0, stream>>>(out_img, tgt_img, partials);
    reduce_partials_kernel<<<1, TPB, 0, stream>>>(partials, res);
}